// Round 1
// baseline (317.932 us; speedup 1.0000x reference)
//
#include <hip/hip_runtime.h>
#include <math.h>

#define B_ 64
#define S_ 128
#define E_ 256
#define D_ 128
#define N_ 4096

typedef _Float16 f16;
typedef _Float16 f16x8 __attribute__((ext_vector_type(8)));
typedef float f32x4 __attribute__((ext_vector_type(4)));

__device__ __forceinline__ unsigned pack2(f16 a, f16 b) {
    union { f16 h[2]; unsigned u; } x;
    x.h[0] = a; x.h[1] = b; return x.u;
}

__device__ __forceinline__ f32x4 mfma16(f16x8 a, f16x8 b, f32x4 c) {
    return __builtin_amdgcn_mfma_f32_16x16x32_f16(a, b, c, 0, 0, 0);
}

// ---------------------------------------------------------------------------
// K1: ep = e*W^T + b, emitted as f16 hi/lo splits in two layouts:
//   epA_h/epA_l: [b][s][d] halves (phase-1 A fragments, d-contiguous)
//   epT_h:       [b][d][s] halves (phase-2 A fragments, s-contiguous)
// 512 WGs (b x d-quarter x s-half). Thread owns d = d0+2p+m, s = s0+2q+v+32u.
// UNCHANGED this round (not in top-5 profile; isolating the k2 experiment).
// ---------------------------------------------------------------------------
__global__ __launch_bounds__(256) void k1_ep(
    const float* __restrict__ e, const float* __restrict__ W,
    const float* __restrict__ bias,
    unsigned* __restrict__ epA_h, unsigned* __restrict__ epA_l,
    unsigned* __restrict__ epT_h)
{
    __shared__ __align__(16) float el[64 * 68];
    __shared__ __align__(16) float Wl[32 * 68];
    const int t = threadIdx.x;
    const int b  = blockIdx.x >> 3;
    const int d0 = ((blockIdx.x >> 1) & 3) << 5;
    const int s0 = (blockIdx.x & 1) << 6;
    const int p = t & 15;   // d = d0 + 2p + m
    const int q = t >> 4;   // s = s0 + 2q + v + 32u

    float acc[2][2][2];
#pragma unroll
    for (int m = 0; m < 2; ++m)
#pragma unroll
        for (int u = 0; u < 2; ++u)
            acc[m][u][0] = acc[m][u][1] = 0.f;

    for (int kc = 0; kc < E_; kc += 64) {
#pragma unroll
        for (int it = 0; it < 4; ++it) {            // e[b][s0..s0+64, kc..kc+64]
            const int lin = it * 256 + t;
            const int r = lin >> 4, c4 = (lin & 15) << 2;
            *(float4*)(el + r * 68 + c4) =
                *(const float4*)(e + (b * S_ + s0 + r) * E_ + kc + c4);
        }
#pragma unroll
        for (int it = 0; it < 2; ++it) {            // W[d0..d0+32, kc..kc+64]
            const int lin = it * 256 + t;
            const int r = lin >> 4, c4 = (lin & 15) << 2;
            *(float4*)(Wl + r * 68 + c4) =
                *(const float4*)(W + (d0 + r) * E_ + kc + c4);
        }
        __syncthreads();
#pragma unroll 4
        for (int kk = 0; kk < 64; kk += 4) {
            const float4 w0 = *(const float4*)(Wl + (2 * p) * 68 + kk);
            const float4 w1 = *(const float4*)(Wl + (2 * p + 1) * 68 + kk);
#pragma unroll
            for (int u = 0; u < 2; ++u) {
                const float4 e0 = *(const float4*)(el + (2 * q + 32 * u) * 68 + kk);
                const float4 e1 = *(const float4*)(el + (2 * q + 1 + 32 * u) * 68 + kk);
                acc[0][u][0] += w0.x * e0.x + w0.y * e0.y + w0.z * e0.z + w0.w * e0.w;
                acc[0][u][1] += w0.x * e1.x + w0.y * e1.y + w0.z * e1.z + w0.w * e1.w;
                acc[1][u][0] += w1.x * e0.x + w1.y * e0.y + w1.z * e0.z + w1.w * e0.w;
                acc[1][u][1] += w1.x * e1.x + w1.y * e1.y + w1.z * e1.z + w1.w * e1.w;
            }
        }
        __syncthreads();
    }

    const float bz[2] = { bias[d0 + 2 * p], bias[d0 + 2 * p + 1] };
    f16 hi[2][2][2], lo[2][2][2];
#pragma unroll
    for (int m = 0; m < 2; ++m)
#pragma unroll
        for (int u = 0; u < 2; ++u)
#pragma unroll
            for (int v = 0; v < 2; ++v) {
                const float val = acc[m][u][v] + bz[m];
                const f16 h_ = (f16)val;
                hi[m][u][v] = h_;
                lo[m][u][v] = (f16)(val - (float)h_);
            }
#pragma unroll
    for (int u = 0; u < 2; ++u)
#pragma unroll
        for (int v = 0; v < 2; ++v) {
            const int s = s0 + 2 * q + v + 32 * u;
            const int w = (b * S_ + s) * 64 + (d0 >> 1) + p;   // pack over d-pair
            epA_h[w] = pack2(hi[0][u][v], hi[1][u][v]);
            epA_l[w] = pack2(lo[0][u][v], lo[1][u][v]);
        }
#pragma unroll
    for (int m = 0; m < 2; ++m)
#pragma unroll
        for (int u = 0; u < 2; ++u) {
            const int d = d0 + 2 * p + m;
            const int w = (b * D_ + d) * 64 + (s0 >> 1) + q + 16 * u; // pack over s-pair
            epT_h[w] = pack2(hi[m][u][0], hi[m][u][1]);
        }
}

// ---------------------------------------------------------------------------
// K2 v2: one WG per (b, 32-col n-tile). 8192 WGs, 256 thr (4 waves).
//  - hT hi/lo: [32 n][128 d] f16, NO pad, XOR-swizzle byte^=((n&7)<<4)
//    (reads 2-way free; writes at the 1024B/8cyc LDS floor)
//  - staging: one pass, all global loads hoisted, single stg bounce (2 bar)
//  - softmax fully in-register: shfl_xor over quads + 512B red[n][4] arrays
//    (no sc round-trip); bT writes are 2-way (conflict-free)
//  - phase-2 stores straight to global (no cb bounce, no final barrier)
// LDS: regA 16384 (hT h/l) + regB 18432 (stg f32[128][36] | bT[32][136]+red)
//      = 34816 B -> 4 WG/CU = 16 waves/CU (matches VGPR cap at <=128 VGPR).
// Barriers: 5 (was ~14).
// ---------------------------------------------------------------------------
__global__ __launch_bounds__(256) void k2_attn(
    const float* __restrict__ h, const f16* __restrict__ epA_h,
    const f16* __restrict__ epA_l, const f16* __restrict__ epT_h,
    float* __restrict__ out)
{
    __shared__ __align__(16) unsigned char regA[16384];
    __shared__ __align__(16) unsigned char regB[18432];

    f16*   hTh  = (f16*)regA;            // [32][128] f16, swizzled
    f16*   hTl  = (f16*)(regA + 8192);
    float* stg  = (float*)regB;          // [128][36] f32 (staging only)
    f16*   bT   = (f16*)regB;            // [32][136] f16 (beta^T, after phase1)
    float* red1 = (float*)(regB + 8704); // [32][4] col-max partials
    float* red2 = (float*)(regB + 9216); // [32][4] col-sum partials

    const int t = threadIdx.x;
    const int b  = blockIdx.x >> 7;
    const int n0 = (blockIdx.x & 127) << 5;
    const int wid = t >> 6, lane = t & 63;
    const int l16 = lane & 15, quad = lane >> 4;

    // ---- stage h[b][:, n0:n0+32] (16 KB f32): global->reg->stg ----
    float4 v[4];
#pragma unroll
    for (int i = 0; i < 4; ++i) {
        const int lin = i * 256 + t;
        const int d = lin >> 3, c4 = (lin & 7) << 2;
        v[i] = *(const float4*)(h + (b * D_ + d) * N_ + n0 + c4);
    }
#pragma unroll
    for (int i = 0; i < 4; ++i) {
        const int lin = i * 256 + t;
        const int d = lin >> 3, c4 = (lin & 7) << 2;
        *(float4*)(stg + d * 36 + c4) = v[i];
    }
    __syncthreads();

    // transpose + f16 hi/lo split -> swizzled hT  (thread: col n, 16 d's)
    {
        const int n = t & 31, dgrp = t >> 5;      // dgrp 0..7
        f16x8 h0, h1, l0, l1;
#pragma unroll
        for (int x = 0; x < 16; ++x) {
            const float val = stg[(dgrp * 16 + x) * 36 + n];
            const f16 hi_ = (f16)val;
            const f16 lo_ = (f16)(val - (float)hi_);
            if (x < 8) { h0[x] = hi_; l0[x] = lo_; }
            else       { h1[x - 8] = hi_; l1[x - 8] = lo_; }
        }
        const int base = n * 256 + dgrp * 32;     // byte offset, d0 = dgrp*16
        const int swz  = (n & 7) << 4;
        *(f16x8*)((char*)hTh + ((base)      ^ swz)) = h0;
        *(f16x8*)((char*)hTh + ((base + 16) ^ swz)) = h1;
        *(f16x8*)((char*)hTl + ((base)      ^ swz)) = l0;
        *(f16x8*)((char*)hTl + ((base + 16) ^ swz)) = l1;
    }
    __syncthreads();

    // ---- phase 1: sc[128 s][32 n] = ep x h (f16 hi/lo, 3 mfma chains) ----
    const int sb = wid << 5;
    f32x4 acc[2][2];
#pragma unroll
    for (int mt = 0; mt < 2; ++mt)
#pragma unroll
        for (int nt = 0; nt < 2; ++nt) acc[mt][nt] = (f32x4)0.f;

    const f16* Ah = epA_h + (b * S_ + sb + l16) * D_ + quad * 8;
    const f16* Al = epA_l + (b * S_ + sb + l16) * D_ + quad * 8;
#pragma unroll
    for (int kk = 0; kk < 4; ++kk) {
        const int dc = kk << 5;
        f16x8 bh[2], bl[2];
#pragma unroll
        for (int nt = 0; nt < 2; ++nt) {
            const int n = (nt << 4) + l16;
            const int off = (n * 256 + dc * 2 + quad * 16) ^ ((n & 7) << 4);
            bh[nt] = *(const f16x8*)((const char*)hTh + off);
            bl[nt] = *(const f16x8*)((const char*)hTl + off);
        }
#pragma unroll
        for (int mt = 0; mt < 2; ++mt) {
            const f16x8 ah = *(const f16x8*)(Ah + mt * 16 * D_ + dc);
            const f16x8 al = *(const f16x8*)(Al + mt * 16 * D_ + dc);
#pragma unroll
            for (int nt = 0; nt < 2; ++nt) {
                acc[mt][nt] = mfma16(ah, bh[nt], acc[mt][nt]);
                acc[mt][nt] = mfma16(ah, bl[nt], acc[mt][nt]);
                acc[mt][nt] = mfma16(al, bh[nt], acc[mt][nt]);
            }
        }
    }

    // ---- softmax over s, in-register (cross-quad shfl + cross-wave red) ----
    // thread holds rows s = sb + mt*16 + quad*4 + r for cols n = nt*16 + l16
#pragma unroll
    for (int nt = 0; nt < 2; ++nt) {
        float pm = -1e30f;
#pragma unroll
        for (int mt = 0; mt < 2; ++mt)
#pragma unroll
            for (int r = 0; r < 4; ++r) pm = fmaxf(pm, acc[mt][nt][r]);
        pm = fmaxf(pm, __shfl_xor(pm, 16));
        pm = fmaxf(pm, __shfl_xor(pm, 32));
        if (quad == 0) red1[(((nt << 4) + l16) << 2) + wid] = pm;
    }
    __syncthreads();

    float ev[2][2][4];
#pragma unroll
    for (int nt = 0; nt < 2; ++nt) {
        const f32x4 m4 = *(const f32x4*)(red1 + (((nt << 4) + l16) << 2));
        const float mx = fmaxf(fmaxf(m4[0], m4[1]), fmaxf(m4[2], m4[3]));
        float ps = 0.f;
#pragma unroll
        for (int mt = 0; mt < 2; ++mt)
#pragma unroll
            for (int r = 0; r < 4; ++r) {
                const float e_ = __expf(acc[mt][nt][r] - mx);
                ev[mt][nt][r] = e_;
                ps += e_;
            }
        ps += __shfl_xor(ps, 16);
        ps += __shfl_xor(ps, 32);
        if (quad == 0) red2[(((nt << 4) + l16) << 2) + wid] = ps;
    }
    __syncthreads();

    unsigned* bTw = (unsigned*)bT;
#pragma unroll
    for (int nt = 0; nt < 2; ++nt) {
        const int n = (nt << 4) + l16;
        const f32x4 s4 = *(const f32x4*)(red2 + (n << 2));
        const float inv = 1.f / (s4[0] + s4[1] + s4[2] + s4[3]);
#pragma unroll
        for (int mt = 0; mt < 2; ++mt) {
            // s0 = sb + mt*16 + quad*4 ; word = n*68 + s0/2 (2-way, free)
            const int wbase = n * 68 + ((sb + mt * 16) >> 1) + quad * 2;
            bTw[wbase]     = pack2((f16)(ev[mt][nt][0] * inv),
                                   (f16)(ev[mt][nt][1] * inv));
            bTw[wbase + 1] = pack2((f16)(ev[mt][nt][2] * inv),
                                   (f16)(ev[mt][nt][3] * inv));
        }
    }
    __syncthreads();

    // ---- phase 2: c[128 d][32 n] = epT x beta (single f16) ----
    const int db = wid << 5;
    f32x4 a2[2][2];
#pragma unroll
    for (int mt = 0; mt < 2; ++mt)
#pragma unroll
        for (int nt = 0; nt < 2; ++nt) a2[mt][nt] = (f32x4)0.f;

    const f16* At = epT_h + (b * D_ + db + l16) * S_ + quad * 8;
#pragma unroll
    for (int kk = 0; kk < 4; ++kk) {
        const int scb = kk << 5;
        f16x8 bb[2];
#pragma unroll
        for (int nt = 0; nt < 2; ++nt)
            bb[nt] = *(const f16x8*)(bT + ((nt << 4) + l16) * 136 + scb + quad * 8);
#pragma unroll
        for (int mt = 0; mt < 2; ++mt) {
            const f16x8 av = *(const f16x8*)(At + mt * 16 * S_ + scb);
#pragma unroll
            for (int nt = 0; nt < 2; ++nt)
                a2[mt][nt] = mfma16(av, bb[nt], a2[mt][nt]);
        }
    }

    // ---- direct global store (4x64B segments per instr; no LDS, no barrier)
    float* ob = out + (b * D_ + db) * N_ + n0;
#pragma unroll
    for (int mt = 0; mt < 2; ++mt)
#pragma unroll
        for (int nt = 0; nt < 2; ++nt)
#pragma unroll
            for (int r = 0; r < 4; ++r)
                ob[(mt * 16 + quad * 4 + r) * N_ + (nt << 4) + l16] =
                    a2[mt][nt][r];
}

extern "C" void kernel_launch(void* const* d_in, const int* in_sizes, int n_in,
                              void* d_out, int out_size, void* d_ws, size_t ws_size,
                              hipStream_t stream) {
    const float* e    = (const float*)d_in[0];
    const float* h    = (const float*)d_in[1];
    const float* W    = (const float*)d_in[2];
    const float* bias = (const float*)d_in[3];
    float* out = (float*)d_out;

    unsigned* epA_h = (unsigned*)d_ws;                  // 2 MB
    unsigned* epA_l = epA_h + (B_ * S_ * D_ / 2);       // 2 MB
    unsigned* epT_h = epA_l + (B_ * S_ * D_ / 2);       // 2 MB

    hipLaunchKernelGGL(k1_ep, dim3(B_ * 8), dim3(256), 0, stream,
                       e, W, bias, epA_h, epA_l, epT_h);
    hipLaunchKernelGGL(k2_attn, dim3(B_ * 128), dim3(256), 0, stream,
                       h, (const f16*)epA_h, (const f16*)epA_l,
                       (const f16*)epT_h, out);
}